// Round 1
// 1923.915 us; speedup vs baseline: 1.1973x; 1.1973x over previous
//
#include <hip/hip_runtime.h>
#include <math.h>

// Problem constants: T=64, B=1024, H=512, V=512
constexpr int T_STEPS = 64;
constexpr int B_SZ = 1024;
constexpr int H_SZ = 512;
constexpr int V_SZ = 512;
constexpr int G_SZ = 4 * H_SZ; // 2048

typedef _Float16 half8 __attribute__((ext_vector_type(8)));
typedef _Float16 half4 __attribute__((ext_vector_type(4)));
typedef float f32x4 __attribute__((ext_vector_type(4)));

__device__ __forceinline__ float4 ld4(const float* p) {
    return *reinterpret_cast<const float4*>(p);
}
__device__ __forceinline__ void st4(float* p, float4 v) {
    *reinterpret_cast<float4*>(p) = v;
}
__device__ __forceinline__ float sigf(float x) { return 1.f / (1.f + expf(-x)); }

// packed argmax word: high 32 = orderable float key, low 32 = (511 - col)
__device__ __forceinline__ unsigned long long pack_vc(float v, int col) {
    unsigned u = __float_as_uint(v);
    unsigned key = (u & 0x80000000u) ? ~u : (u | 0x80000000u);
    return ((unsigned long long)key << 32) | (unsigned)(511 - col);
}

// async global->LDS DMA, 16B per lane, wave-linear LDS destination
#define GLDS(g, l) __builtin_amdgcn_global_load_lds(                      \
    (const __attribute__((address_space(1))) void*)(g),                   \
    (__attribute__((address_space(3))) void*)(l), 16, 0, 0)

// ---------------------------------------------------------------------------
// fp32 -> (hi fp16, lo fp16) split: x ~= hi + lo/2048
// ---------------------------------------------------------------------------
__global__ __launch_bounds__(256) void cvt_pair(
    const float* __restrict__ x, _Float16* __restrict__ hi,
    _Float16* __restrict__ lo)
{
    const int i4 = blockIdx.x * 256 + threadIdx.x;
    const float4 v = ld4(x + (size_t)i4 * 4);
    half4 h, l;
    const float h0 = (float)(_Float16)v.x; h[0] = (_Float16)v.x; l[0] = (_Float16)((v.x - h0) * 2048.f);
    const float h1 = (float)(_Float16)v.y; h[1] = (_Float16)v.y; l[1] = (_Float16)((v.y - h1) * 2048.f);
    const float h2 = (float)(_Float16)v.z; h[2] = (_Float16)v.z; l[2] = (_Float16)((v.z - h2) * 2048.f);
    const float h3 = (float)(_Float16)v.w; h[3] = (_Float16)v.w; l[3] = (_Float16)((v.w - h3) * 2048.f);
    *reinterpret_cast<half4*>(hi + (size_t)i4 * 4) = h;
    *reinterpret_cast<half4*>(lo + (size_t)i4 * 4) = l;
}

// ---------------------------------------------------------------------------
// fp32 tiled NT GEMM — used once for E_gates = emb @ W_ih^T + (b_ih+b_hh)
// ---------------------------------------------------------------------------
__global__ __launch_bounds__(256) void gemm_nt_f32(
    const float* __restrict__ A, const float* __restrict__ Bw,
    float* __restrict__ C, int M, int N, int K,
    const float* __restrict__ bias1, const float* __restrict__ bias2)
{
    constexpr int BK = 16;
    __shared__ __align__(16) float As[BK][64];
    __shared__ __align__(16) float Bs[BK][64];
    const int tid = threadIdx.x;
    const int tx = tid % 16, ty = tid / 16;
    const int m0 = blockIdx.y * 64, n0 = blockIdx.x * 64;
    const int lr = tid / 4, lc = (tid % 4) * 4;
    float acc[4][4] = {};
    for (int k0 = 0; k0 < K; k0 += BK) {
        const float4 av = ld4(&A[(size_t)(m0 + lr) * K + (k0 + lc)]);
        const float4 bv = ld4(&Bw[(size_t)(n0 + lr) * K + (k0 + lc)]);
        __syncthreads();
        As[lc + 0][lr] = av.x; As[lc + 1][lr] = av.y; As[lc + 2][lr] = av.z; As[lc + 3][lr] = av.w;
        Bs[lc + 0][lr] = bv.x; Bs[lc + 1][lr] = bv.y; Bs[lc + 2][lr] = bv.z; Bs[lc + 3][lr] = bv.w;
        __syncthreads();
#pragma unroll
        for (int k = 0; k < BK; ++k) {
            const float4 a4 = ld4(&As[k][ty * 4]);
            const float4 b4 = ld4(&Bs[k][tx * 4]);
            const float ar[4] = {a4.x, a4.y, a4.z, a4.w};
            const float br[4] = {b4.x, b4.y, b4.z, b4.w};
#pragma unroll
            for (int i = 0; i < 4; ++i)
#pragma unroll
                for (int j = 0; j < 4; ++j)
                    acc[i][j] = fmaf(ar[i], br[j], acc[i][j]);
        }
    }
    const int nc = n0 + tx * 4;
    const float4 b1 = ld4(&bias1[nc]);
    const float4 b2 = ld4(&bias2[nc]);
#pragma unroll
    for (int i = 0; i < 4; ++i) {
        const int m = m0 + ty * 4 + i;
        float4 v;
        v.x = acc[i][0] + b1.x + b2.x; v.y = acc[i][1] + b1.y + b2.y;
        v.z = acc[i][2] + b1.z + b2.z; v.w = acc[i][3] + b1.w + b2.w;
        st4(&C[(size_t)m * N + nc], v);
    }
}

// ---------------------------------------------------------------------------
// Kernel A: gates GEMM (fp16x2 MFMA) + LSTM cell, fused.
// Block: 256 thr (4 waves). Tile: 64 batch x (4 gates x 32 h-cols) => N=128.
// Grid (H/32=16, B/64=16). NEW: BK=64 double-buffered LDS filled by
// global_load_lds DMA (1-deep prefetch), chunk-rotation swizzle
// (chunk' = (chunk + row%8) & 7) applied via pre-swizzled global source
// addresses + matching precomputed ds_read offsets -> conflict-free b128.
// One barrier per K-tile (8 total vs 32 before).
// ---------------------------------------------------------------------------
__global__ __launch_bounds__(256) void step_gates_cell(
    const _Float16* __restrict__ Ahi, const _Float16* __restrict__ Alo,
    const _Float16* __restrict__ Whh_hi, const _Float16* __restrict__ Whh_lo,
    const float* __restrict__ Eg,
    const unsigned long long* __restrict__ tok_cur,
    unsigned long long* __restrict__ tok_reset,
    float* __restrict__ cbuf,
    _Float16* __restrict__ Nhi, _Float16* __restrict__ Nlo)
{
    // buffer layout (bytes): Ah[0,8K) Al[8K,16K) Bh[16K,32K) Bl[32K,48K)
    constexpr int RBUF = 49152;
    __shared__ __align__(16) char smem[2 * RBUF]; // 96 KB, dbuf; sg reuses it
    float* sg = (float*)smem;                     // 64 x 129 fp32 (33 KB)

    const int tid = threadIdx.x;
    const int wave = tid >> 6, lane = tid & 63;
    const int wm = wave >> 1, wn = wave & 1;
    const int lm = lane & 15, kq = lane >> 4;
    const int h0 = blockIdx.x * 32;
    const int b0 = blockIdx.y * 64;

    // ---- staging tables: 12 DMA instrs per thread per K64 tile ----
    // each DMA covers 8 rows x 128 B; lane l -> row j*8+(l>>3), slot l&7.
    // source chunk for slot s in row r: c = (s - r%8) & 7  (inverse swizzle)
    const int lrow = lane >> 3;
    const int co = ((lane & 7) - lrow) & 7;
    const _Float16* gsrc[12];
    int loff[12];
    {
        int idx = 0;
#pragma unroll
        for (int hv = 0; hv < 2; ++hv)           // A: hi, lo
#pragma unroll
            for (int rep = 0; rep < 2; ++rep) {
                const int j = wave + rep * 4;    // 0..7
                const int rs = j * 8 + lrow;     // 0..63
                gsrc[idx] = (hv ? Alo : Ahi) + (size_t)(b0 + rs) * 512 + co * 8;
                loff[idx] = hv * 8192 + j * 1024;
                ++idx;
            }
#pragma unroll
        for (int hv = 0; hv < 2; ++hv)           // B: hi, lo
#pragma unroll
            for (int rep = 0; rep < 4; ++rep) {
                const int j = wave + rep * 4;    // 0..15
                const int rs = j * 8 + lrow;     // 0..127
                const int grow = (rs >> 5) * 512 + h0 + (rs & 31);
                gsrc[idx] = (hv ? Whh_lo : Whh_hi) + (size_t)grow * 512 + co * 8;
                loff[idx] = 16384 + hv * 16384 + j * 1024;
                ++idx;
            }
    }

    // ---- read-side swizzled ds offsets (loop-invariant per lane) ----
    int ar_off[2][2], br_off[4][2]; // [frag][k32-half s]; lo = +8192 / +16384
#pragma unroll
    for (int gm = 0; gm < 2; ++gm)
#pragma unroll
        for (int s = 0; s < 2; ++s) {
            const int rm = wm * 32 + gm * 16 + lm;           // rm&7 == lm&7
            const int ch = ((s * 4 + kq) + (lm & 7)) & 7;
            ar_off[gm][s] = rm * 128 + ch * 16;
        }
#pragma unroll
    for (int gn = 0; gn < 4; ++gn)
#pragma unroll
        for (int s = 0; s < 2; ++s) {
            const int rr = wn * 64 + gn * 16 + lm;
            const int ch = ((s * 4 + kq) + (lm & 7)) & 7;
            br_off[gn][s] = 16384 + rr * 128 + ch * 16;
        }

    f32x4 aH[2][4] = {};
    f32x4 aC[2][4] = {};

    // prologue: stage K-tile 0 into buffer 0
#pragma unroll
    for (int i = 0; i < 12; ++i) GLDS(gsrc[i], smem + loff[i]);
    __syncthreads(); // vmcnt(0) drain -> tile 0 ready

#pragma unroll
    for (int it = 0; it < 8; ++it) {
        // prefetch next K64 tile into the other buffer (issued before compute)
        if (it < 7) {
            char* dst = smem + ((it + 1) & 1) * RBUF;
            const int ka = (it + 1) * 64; // halves
#pragma unroll
            for (int i = 0; i < 12; ++i) GLDS(gsrc[i] + ka, dst + loff[i]);
        }
        const char* bp = smem + (it & 1) * RBUF;
#pragma unroll
        for (int s = 0; s < 2; ++s) {
            half8 bh[4], bl[4];
#pragma unroll
            for (int gn = 0; gn < 4; ++gn) {
                bh[gn] = *(const half8*)(bp + br_off[gn][s]);
                bl[gn] = *(const half8*)(bp + br_off[gn][s] + 16384);
            }
#pragma unroll
            for (int gm = 0; gm < 2; ++gm) {
                const half8 ah = *(const half8*)(bp + ar_off[gm][s]);
                const half8 al = *(const half8*)(bp + ar_off[gm][s] + 8192);
#pragma unroll
                for (int gn = 0; gn < 4; ++gn)
                    aH[gm][gn] = __builtin_amdgcn_mfma_f32_16x16x32_f16(ah, bh[gn], aH[gm][gn], 0, 0, 0);
#pragma unroll
                for (int gn = 0; gn < 4; ++gn)
                    aC[gm][gn] = __builtin_amdgcn_mfma_f32_16x16x32_f16(ah, bl[gn], aC[gm][gn], 0, 0, 0);
#pragma unroll
                for (int gn = 0; gn < 4; ++gn)
                    aC[gm][gn] = __builtin_amdgcn_mfma_f32_16x16x32_f16(al, bh[gn], aC[gm][gn], 0, 0, 0);
            }
        }
        __syncthreads(); // reads done + prefetch DMA drained (vmcnt 0)
    }

    // ---- epilogue: gate exchange via LDS (repurposed), cell math ----
#pragma unroll
    for (int gm = 0; gm < 2; ++gm) {
#pragma unroll
        for (int gn = 0; gn < 4; ++gn) {
            const int row = wm * 32 + gm * 16 + kq * 4;
            const int col = wn * 64 + gn * 16 + lm;
#pragma unroll
            for (int r = 0; r < 4; ++r)
                sg[(row + r) * 129 + col] =
                    aH[gm][gn][r] + aC[gm][gn][r] * (1.f / 2048.f);
        }
    }
    __syncthreads();

    // cell phase: thread -> row = tid>>2 (0..63), hh base = (tid&3)*8
    const int crow = tid >> 2;
    const int hb = (tid & 3) * 8;
    const int b = b0 + crow;
    const unsigned long long pk = tok_cur[b];
    const int tk = 511 - (int)(unsigned)(pk & 0xFFFFFFFFu);
    const float* egp = Eg + (size_t)tk * G_SZ + h0;

#pragma unroll
    for (int q = 0; q < 2; ++q) {
        const int hh = hb + q * 4;
        const float* sr = sg + crow * 129;
        const float4 gI = ld4(sr + hh);
        const float4 gF = ld4(sr + 32 + hh);
        const float4 gG = ld4(sr + 64 + hh);
        const float4 gO = ld4(sr + 96 + hh);
        const float4 eI = ld4(egp + hh);
        const float4 eF = ld4(egp + 512 + hh);
        const float4 eG = ld4(egp + 1024 + hh);
        const float4 eO = ld4(egp + 1536 + hh);
        const size_t ci = (size_t)b * 512 + h0 + hh;
        const float4 cv = ld4(cbuf + ci);

        const float iv[4] = {gI.x + eI.x, gI.y + eI.y, gI.z + eI.z, gI.w + eI.w};
        const float fv[4] = {gF.x + eF.x, gF.y + eF.y, gF.z + eF.z, gF.w + eF.w};
        const float gv[4] = {gG.x + eG.x, gG.y + eG.y, gG.z + eG.z, gG.w + eG.w};
        const float ov[4] = {gO.x + eO.x, gO.y + eO.y, gO.z + eO.z, gO.w + eO.w};
        float cc[4] = {cv.x, cv.y, cv.z, cv.w};
        float hn[4];
#pragma unroll
        for (int j = 0; j < 4; ++j) {
            const float cn = sigf(fv[j]) * cc[j] + sigf(iv[j]) * tanhf(gv[j]);
            cc[j] = cn;
            hn[j] = sigf(ov[j]) * tanhf(cn);
        }
        st4(cbuf + ci, make_float4(cc[0], cc[1], cc[2], cc[3]));
        half4 h, l;
#pragma unroll
        for (int j = 0; j < 4; ++j) {
            const _Float16 hi = (_Float16)hn[j];
            h[j] = hi;
            l[j] = (_Float16)((hn[j] - (float)hi) * 2048.f);
        }
        *reinterpret_cast<half4*>(Nhi + ci) = h;
        *reinterpret_cast<half4*>(Nlo + ci) = l;
    }

    if (blockIdx.x == 0 && tid < 64) tok_reset[b0 + tid] = 0ULL;
}

// ---------------------------------------------------------------------------
// Kernel B: logits GEMM (fp16x2 MFMA, LDS-free) + bias + out write + packed
// atomicMax argmax. NEW: 256 thr (4 waves, 16x32 per wave) -> 4 waves/CU.
// Grid (V/64=8, B/32=32) = 256 blocks.
// ---------------------------------------------------------------------------
__global__ __launch_bounds__(256) void step_logits_argmax(
    const _Float16* __restrict__ Ahi, const _Float16* __restrict__ Alo,
    const _Float16* __restrict__ Whi, const _Float16* __restrict__ Wlo,
    const float* __restrict__ b_out,
    float* __restrict__ outT,
    unsigned long long* __restrict__ tokmax)
{
    const int tid = threadIdx.x, wave = tid >> 6, lane = tid & 63;
    const int wm = wave >> 1, wn = wave & 1;
    const int lm = lane & 15, kq = lane >> 4;
    const int n0 = blockIdx.x * 64 + wn * 32;
    const int m0 = blockIdx.y * 32 + wm * 16;

    f32x4 aH[2] = {};
    f32x4 aC[2] = {};

    const _Float16* pAh = Ahi + (size_t)(m0 + lm) * 512 + kq * 8;
    const _Float16* pAl = Alo + (size_t)(m0 + lm) * 512 + kq * 8;
    const _Float16* pW0h = Whi + (size_t)(n0 + lm) * 512 + kq * 8;
    const _Float16* pW0l = Wlo + (size_t)(n0 + lm) * 512 + kq * 8;
    const _Float16* pW1h = Whi + (size_t)(n0 + 16 + lm) * 512 + kq * 8;
    const _Float16* pW1l = Wlo + (size_t)(n0 + 16 + lm) * 512 + kq * 8;

#pragma unroll
    for (int k0 = 0; k0 < 512; k0 += 32) {
        const half8 ah = *(const half8*)(pAh + k0);
        const half8 al = *(const half8*)(pAl + k0);
        const half8 b0h = *(const half8*)(pW0h + k0);
        const half8 b0l = *(const half8*)(pW0l + k0);
        const half8 b1h = *(const half8*)(pW1h + k0);
        const half8 b1l = *(const half8*)(pW1l + k0);
        aH[0] = __builtin_amdgcn_mfma_f32_16x16x32_f16(ah, b0h, aH[0], 0, 0, 0);
        aH[1] = __builtin_amdgcn_mfma_f32_16x16x32_f16(ah, b1h, aH[1], 0, 0, 0);
        aC[0] = __builtin_amdgcn_mfma_f32_16x16x32_f16(ah, b0l, aC[0], 0, 0, 0);
        aC[1] = __builtin_amdgcn_mfma_f32_16x16x32_f16(ah, b1l, aC[1], 0, 0, 0);
        aC[0] = __builtin_amdgcn_mfma_f32_16x16x32_f16(al, b0h, aC[0], 0, 0, 0);
        aC[1] = __builtin_amdgcn_mfma_f32_16x16x32_f16(al, b1h, aC[1], 0, 0, 0);
    }

    unsigned long long best[4] = {0ULL, 0ULL, 0ULL, 0ULL};
#pragma unroll
    for (int gn = 0; gn < 2; ++gn) {
        const int col = n0 + gn * 16 + lm;
        const float bo = b_out[col];
#pragma unroll
        for (int r = 0; r < 4; ++r) {
            const float v = aH[gn][r] + aC[gn][r] * (1.f / 2048.f) + bo;
            const int row = m0 + kq * 4 + r;
            outT[(size_t)row * V_SZ + col] = v;
            const unsigned long long p = pack_vc(v, col);
            if (p > best[r]) best[r] = p;
        }
    }
#pragma unroll
    for (int r = 0; r < 4; ++r) {
#pragma unroll
        for (int off = 1; off < 16; off <<= 1) {
            const unsigned long long o = __shfl_xor(best[r], off);
            if (o > best[r]) best[r] = o;
        }
    }
    if (lm == 0) {
#pragma unroll
        for (int r = 0; r < 4; ++r)
            atomicMax(&tokmax[m0 + kq * 4 + r], best[r]);
    }
}

// ---------------------------------------------------------------------------
__global__ __launch_bounds__(256) void init_tok(unsigned long long* __restrict__ tok)
{
    const int i = blockIdx.x * 256 + threadIdx.x; // 0..2047
    tok[i] = (i < 1024) ? 511ULL : 0ULL; // buf0: token 0 (SOS); buf1: cleared
}

// ---------------------------------------------------------------------------
extern "C" void kernel_launch(void* const* d_in, const int* in_sizes, int n_in,
                              void* d_out, int out_size, void* d_ws, size_t ws_size,
                              hipStream_t stream)
{
    const float* enc_h = (const float*)d_in[2];
    const float* enc_c = (const float*)d_in[3];
    const float* emb   = (const float*)d_in[4];
    const float* W_ih  = (const float*)d_in[5];
    const float* W_hh  = (const float*)d_in[6];
    const float* b_ih  = (const float*)d_in[7];
    const float* b_hh  = (const float*)d_in[8];
    const float* W_out = (const float*)d_in[9];
    const float* b_out = (const float*)d_in[10];
    float* out = (float*)d_out;

    // workspace layout (1 MB units where convenient)
    char* ws = (char*)d_ws;
    _Float16* Whh_hi  = (_Float16*)(ws);                          // 2 MB
    _Float16* Whh_lo  = (_Float16*)(ws + (2u << 20));             // 2 MB
    _Float16* Wout_hi = (_Float16*)(ws + (4u << 20));             // 0.5 MB
    _Float16* Wout_lo = (_Float16*)(ws + (4u << 20) + (512u << 10));
    _Float16* Hhi[2] = {(_Float16*)(ws + (5u << 20)), (_Float16*)(ws + (7u << 20))};
    _Float16* Hlo[2] = {(_Float16*)(ws + (6u << 20)), (_Float16*)(ws + (8u << 20))};
    float* cbuf = (float*)(ws + (9u << 20));                      // 2 MB
    float* Eg   = (float*)(ws + (11u << 20));                     // 4 MB
    unsigned long long* tokbuf = (unsigned long long*)(ws + (15u << 20)); // 16 KB

    const dim3 blk256(256);

    // one-time conversions + init
    cvt_pair<<<(G_SZ * H_SZ) / 1024, blk256, 0, stream>>>(W_hh, Whh_hi, Whh_lo);
    cvt_pair<<<(V_SZ * H_SZ) / 1024, blk256, 0, stream>>>(W_out, Wout_hi, Wout_lo);
    cvt_pair<<<(B_SZ * H_SZ) / 1024, blk256, 0, stream>>>(enc_h, Hhi[0], Hlo[0]);
    hipMemcpyAsync(cbuf, enc_c, (size_t)B_SZ * H_SZ * 4, hipMemcpyDeviceToDevice, stream);
    init_tok<<<8, blk256, 0, stream>>>(tokbuf);

    // E_gates = emb @ W_ih^T + (b_ih + b_hh)   [V x 4H], fp32, once
    gemm_nt_f32<<<dim3(G_SZ / 64, V_SZ / 64), blk256, 0, stream>>>(
        emb, W_ih, Eg, V_SZ, G_SZ, H_SZ, b_ih, b_hh);

    for (int t = 0; t < T_STEPS; ++t) {
        const int cur = t & 1, nxt = (t + 1) & 1;
        // gates + cell: reads h[cur], tok[cur]; writes h[nxt], c, clears tok[nxt]
        step_gates_cell<<<dim3(H_SZ / 32, B_SZ / 64), blk256, 0, stream>>>(
            Hhi[cur], Hlo[cur], Whh_hi, Whh_lo, Eg,
            tokbuf + cur * B_SZ, tokbuf + nxt * B_SZ,
            cbuf, Hhi[nxt], Hlo[nxt]);

        // logits + argmax: reads h[nxt]; writes out[t], tok[nxt]
        step_logits_argmax<<<dim3(V_SZ / 64, B_SZ / 32), blk256, 0, stream>>>(
            Hhi[nxt], Hlo[nxt], Wout_hi, Wout_lo, b_out,
            out + (size_t)t * B_SZ * V_SZ, tokbuf + nxt * B_SZ);
    }
}